// Round 13
// baseline (94.899 us; speedup 1.0000x reference)
//
#include <hip/hip_runtime.h>
#include <hip/hip_cooperative_groups.h>
#include <math.h>

namespace cg = cooperative_groups;

#define B_ 4
#define T_ 512
#define C_ 128
#define HS_ 64

typedef float f4 __attribute__((ext_vector_type(4)));
typedef float f2 __attribute__((ext_vector_type(2)));

// scale = C^-0.5
#define SCALE_ 0.08838834764831845f

static __device__ __forceinline__ f2 relu2(f2 v) {
    v.x = fmaxf(v.x, 0.f);
    v.y = fmaxf(v.y, 0.f);
    return v;
}

// ---------------------------------------------------------------------------
// ONE cooperative kernel, 512 blocks x 256 threads, 2 blocks/CU co-resident.
// Phase 1 (prep): block bx computes rows bx*4..bx*4+3 of
//   Aq = x1@W1q + b1, AkT = (x1@W1k)^T  (scatter store), V = x@Wv.
//   Lane map q = u>>2, r = u&3: 4 consecutive lanes share one W address
//   (TA dedupe); W traffic = 160KB/block = 80MB L2 total. x/x1 in LDS
//   (stride 132: the 4 same-c rows land in distinct banks).
// grid.sync()
// Phase 2 (fused): block = (b = bx&3, g = 127-(bx>>2)) -> row quad 4g..4g+3.
//   Wave w = window j in [128w, 128w+128); lane holds 2 j's. 64-step c-loop:
//   2 f2 AkT loads (512B coalesced/wave) serve ALL 4 rows; aq/W2 are
//   wave-uniform scalar loads. Zero cross-lane ops in the loop.
//   Then per-row window softmax (6+6 shfl), PV with V loads shared 4 ways,
//   in-block flash merge (wave w merges row r0+w). b2 cancels in softmax.
// ---------------------------------------------------------------------------
__global__ __launch_bounds__(256, 2) void k_all(
    const float* __restrict__ x, const float* __restrict__ pos,
    const float* __restrict__ W1, const float* __restrict__ b1,
    const float* __restrict__ W2, const float* __restrict__ Wv,
    float* __restrict__ Aq, float* __restrict__ AkT, float* __restrict__ Vv,
    float* __restrict__ out)
{
    __shared__ float x1s[4][132];
    __shared__ float xs[4][132];
    __shared__ float pbuf[4][4][128];
    __shared__ float accs[4][4][64];
    __shared__ float mls[4][4][2];

    const int t = threadIdx.x;
    const int bx = blockIdx.x;  // 0..511

    // ---------------- phase 1: prep rows bx*4 .. bx*4+3 ----------------
    {
        const int prow0 = bx * 4;
        if (t < 128) {
            const int r = t >> 5, cq = t & 31;
            const int gr = prow0 + r;
            f4 xv = *(const f4*)(x + (size_t)gr * 128 + cq * 4);
            f4 pv = *(const f4*)(pos + (size_t)(gr & 511) * 128 + cq * 4);
            *(f4*)&xs[r][cq * 4] = xv;
            *(f4*)&x1s[r][cq * 4] = xv + pv;
        }
        __syncthreads();

        for (int u = t; u < 320; u += 256) {
            const int q = u >> 2, r = u & 3;
            const int gr = prow0 + r;
            const float* wbase; int wstr, col0; const float* xb;
            f4 acc = {0.f, 0.f, 0.f, 0.f};
            if (q < 32) {
                col0 = q * 4; wbase = W1 + 16384 + col0; wstr = 128; xb = x1s[r];
                acc = *(const f4*)(b1 + col0);
            } else if (q < 64) {
                col0 = (q - 32) * 4; wbase = W1 + col0; wstr = 128; xb = x1s[r];
            } else {
                col0 = (q - 64) * 4; wbase = Wv + col0; wstr = 64; xb = xs[r];
            }
#pragma unroll 8
            for (int c = 0; c < 128; ++c)
                acc += xb[c] * *(const f4*)(wbase + c * wstr);

            if (q < 32) {
                *(f4*)(Aq + (size_t)gr * 128 + col0) = acc;
            } else if (q < 64) {
                const int bb = gr >> 9, j = gr & 511;
                float* base = AkT + ((size_t)bb * 128 + col0) * 512 + j;
                base[0] = acc.x; base[512] = acc.y;
                base[1024] = acc.z; base[1536] = acc.w;
            } else {
                *(f4*)(Vv + (size_t)gr * 64 + col0) = acc;
            }
        }
    }

    cg::this_grid().sync();

    // ---------------- phase 2: fused for quad (b, g) ----------------
    const int b = bx & 3;
    const int g = 127 - (bx >> 2);     // descending: heavy quads first
    const int r0 = g * 4;
    const int w = t >> 6, lane = t & 63;
    const int j0 = w * 128;
    const int jA = j0 + lane * 2;

    float m0 = -1e30f, m1 = -1e30f, m2 = -1e30f, m3 = -1e30f;
    float l0 = 0.f, l1 = 0.f, l2 = 0.f, l3 = 0.f;
    float a0 = 0.f, a1 = 0.f, a2 = 0.f, a3 = 0.f;

    if (j0 <= r0 + 3) {  // wave's window causally live for at least one row
        const float* aq0 = Aq + (size_t)(b * 512 + r0) * 128;
        const float* aq1 = aq0 + 128;
        const float* aq2 = aq1 + 128;
        const float* aq3 = aq2 + 128;
        const float* akt = AkT + (size_t)b * 65536 + jA;

        f2 s0a = {0,0}, s0b = {0,0}, s1a = {0,0}, s1b = {0,0};
        f2 s2a = {0,0}, s2b = {0,0}, s3a = {0,0}, s3b = {0,0};
#pragma unroll 4
        for (int c = 0; c < 128; c += 2) {
            const f2 k0 = *(const f2*)(akt + (size_t)c * 512);
            const f2 k1 = *(const f2*)(akt + (size_t)(c + 1) * 512);
            const float w0 = W2[c], w1 = W2[c + 1];
            s0a += relu2(k0 + aq0[c]) * w0;  s0b += relu2(k1 + aq0[c + 1]) * w1;
            s1a += relu2(k0 + aq1[c]) * w0;  s1b += relu2(k1 + aq1[c + 1]) * w1;
            s2a += relu2(k0 + aq2[c]) * w0;  s2b += relu2(k1 + aq2[c + 1]) * w1;
            s3a += relu2(k0 + aq3[c]) * w0;  s3b += relu2(k1 + aq3[c + 1]) * w1;
        }

#define FINROW(R, SA, SB, MD, LD)                                        \
        {                                                                \
            const int rr_ = r0 + (R);                                    \
            f2 sv = (SA + SB) * SCALE_;                                  \
            float sx = (jA     <= rr_) ? sv.x : -1e30f;                  \
            float sy = (jA + 1 <= rr_) ? sv.y : -1e30f;                  \
            float mx = fmaxf(sx, sy);                                    \
            _Pragma("unroll")                                            \
            for (int off = 1; off < 64; off <<= 1)                       \
                mx = fmaxf(mx, __shfl_xor(mx, off));                     \
            const bool live_ = (j0 <= rr_);                              \
            const float px = live_ ? __expf(sx - mx) : 0.f;              \
            const float py = live_ ? __expf(sy - mx) : 0.f;              \
            f2 pp = {px, py};                                            \
            *(f2*)&pbuf[w][R][lane * 2] = pp;                            \
            float ls = px + py;                                          \
            _Pragma("unroll")                                            \
            for (int off = 1; off < 64; off <<= 1)                       \
                ls += __shfl_xor(ls, off);                               \
            MD = live_ ? mx : -1e30f;                                    \
            LD = ls;                                                     \
        }
        FINROW(0, s0a, s0b, m0, l0)
        FINROW(1, s1a, s1b, m1, l1)
        FINROW(2, s2a, s2b, m2, l2)
        FINROW(3, s3a, s3b, m3, l3)
#undef FINROW

        // ---- PV over the window; lane = h; V loads shared by 4 rows ----
        const float* vt = Vv + ((size_t)b * 512 + j0) * 64 + lane;
#pragma unroll 4
        for (int q4 = 0; q4 < 32; ++q4) {
            const f4 p0 = *(const f4*)&pbuf[w][0][q4 * 4];
            const f4 p1 = *(const f4*)&pbuf[w][1][q4 * 4];
            const f4 p2 = *(const f4*)&pbuf[w][2][q4 * 4];
            const f4 p3 = *(const f4*)&pbuf[w][3][q4 * 4];
            const float v0 = vt[(q4 * 4 + 0) * 64];
            const float v1 = vt[(q4 * 4 + 1) * 64];
            const float v2 = vt[(q4 * 4 + 2) * 64];
            const float v3 = vt[(q4 * 4 + 3) * 64];
            a0 += p0.x * v0 + p0.y * v1 + p0.z * v2 + p0.w * v3;
            a1 += p1.x * v0 + p1.y * v1 + p1.z * v2 + p1.w * v3;
            a2 += p2.x * v0 + p2.y * v1 + p2.z * v2 + p2.w * v3;
            a3 += p3.x * v0 + p3.y * v1 + p3.z * v2 + p3.w * v3;
        }
    }

    // ---- partials to LDS; in-block flash merge ----
    accs[w][0][lane] = a0;
    accs[w][1][lane] = a1;
    accs[w][2][lane] = a2;
    accs[w][3][lane] = a3;
    if (lane == 0) {
        mls[w][0][0] = m0; mls[w][0][1] = l0;
        mls[w][1][0] = m1; mls[w][1][1] = l1;
        mls[w][2][0] = m2; mls[w][2][1] = l2;
        mls[w][3][0] = m3; mls[w][3][1] = l3;
    }
    __syncthreads();

    // wave w merges row r0 + w over its nw live windows
    const int rr = r0 + w;
    const int nw = (rr >> 7) + 1;
    float ms = -1e30f;
    for (int ww = 0; ww < nw; ++ww) ms = fmaxf(ms, mls[ww][w][0]);
    float num = 0.f, den = 0.f;
    for (int ww = 0; ww < nw; ++ww) {
        const float e = __expf(mls[ww][w][0] - ms);
        den += mls[ww][w][1] * e;
        num += accs[ww][w][lane] * e;
    }
    out[(size_t)(b * 512 + rr) * 64 + lane] = num / den;
}

// ---------------------------------------------------------------------------
extern "C" void kernel_launch(void* const* d_in, const int* in_sizes, int n_in,
                              void* d_out, int out_size, void* d_ws, size_t ws_size,
                              hipStream_t stream)
{
    const float* x   = (const float*)d_in[0];
    const float* pos = (const float*)d_in[1];
    const float* W1  = (const float*)d_in[2];
    const float* b1  = (const float*)d_in[3];
    const float* W2  = (const float*)d_in[4];
    const float* b2  = (const float*)d_in[5];  (void)b2;  // cancels in softmax
    const float* Wv  = (const float*)d_in[6];
    float* out = (float*)d_out;
    float* ws = (float*)d_ws;

    float* Aq  = ws;                 // B*T*C = 262144
    float* AkT = ws + 262144;        // B*C*T = 262144 (transposed)
    float* V   = ws + 524288;        // B*T*HS = 131072

    void* args[] = {(void*)&x, (void*)&pos, (void*)&W1, (void*)&b1,
                    (void*)&W2, (void*)&Wv, (void*)&Aq, (void*)&AkT,
                    (void*)&V, (void*)&out};
    hipLaunchCooperativeKernel((const void*)k_all, dim3(512), dim3(256),
                               args, 0, stream);
}

// Round 14
// 34.666 us; speedup vs baseline: 2.7375x; 2.7375x over previous
//
#include <hip/hip_runtime.h>
#include <math.h>

#define B_ 4
#define T_ 512
#define C_ 128
#define HS_ 64

typedef float f4 __attribute__((ext_vector_type(4)));
typedef float f2 __attribute__((ext_vector_type(2)));

// scale = C^-0.5
#define SCALE_ 0.08838834764831845f

static __device__ __forceinline__ f2 relu2(f2 v) {
    v.x = fmaxf(v.x, 0.f);
    v.y = fmaxf(v.y, 0.f);
    return v;
}

// ---------------------------------------------------------------------------
// Kernel 1: prep.  x1 = x + pos_emb;  Aq = x1@W1q + b1;  AkT = (x1@W1k)^T;
// V = x@Wv.  256 blocks x 640 threads, block = 8 rows.  (round 10 verbatim)
// ---------------------------------------------------------------------------
__global__ __launch_bounds__(640) void k_prep(
    const float* __restrict__ x, const float* __restrict__ pos,
    const float* __restrict__ W1, const float* __restrict__ b1,
    const float* __restrict__ Wv,
    float* __restrict__ Aq, float* __restrict__ AkT, float* __restrict__ V)
{
    __shared__ float x1s[8 * 132];
    __shared__ float xs[8 * 132];
    const int t = threadIdx.x;
    const int row0 = blockIdx.x * 8;  // over B*T = 2048

    if (t < 256) {
        int r = t >> 5, cq = t & 31;
        int gr = row0 + r;
        f4 xv = *(const f4*)(x + gr * 128 + cq * 4);
        f4 pv = *(const f4*)(pos + (gr & 511) * 128 + cq * 4);
        *(f4*)&xs[r * 132 + cq * 4] = xv;
        *(f4*)&x1s[r * 132 + cq * 4] = xv + pv;
    }
    __syncthreads();

    const int q = t >> 3;   // 0..79 col-quad
    const int r = t & 7;    // row in tile

    const float* wbase;
    int wstr, col0;
    const float* xb;
    f4 binit = {0.f, 0.f, 0.f, 0.f};
    if (q < 32) {
        col0 = q * 4;
        wbase = W1 + 128 * 128 + col0;  // W1q rows (c-major)
        wstr = 128;
        xb = x1s;
        binit = *(const f4*)(b1 + col0);
    } else if (q < 64) {
        col0 = (q - 32) * 4;
        wbase = W1 + col0;  // W1k rows
        wstr = 128;
        xb = x1s;
    } else {
        col0 = (q - 64) * 4;
        wbase = Wv + col0;
        wstr = 64;
        xb = xs;
    }

    f4 acc = binit;
    const float* xr = xb + r * 132;
#pragma unroll 8
    for (int c = 0; c < 128; ++c) {
        f4 w = *(const f4*)(wbase + c * wstr);
        acc += xr[c] * w;
    }

    const int gr = row0 + r;
    if (q < 32) {
        *(f4*)(Aq + (size_t)gr * 128 + col0) = acc;
    } else if (q < 64) {
        const int bb = gr >> 9, j = gr & 511;
        float* base = AkT + ((size_t)bb * 128 + col0) * 512 + j;
        base[0]    = acc.x;
        base[512]  = acc.y;
        base[1024] = acc.z;
        base[1536] = acc.w;
    } else {
        *(f4*)(V + (size_t)gr * 64 + col0) = acc;
    }
}

// ---------------------------------------------------------------------------
// Kernel 2: fused wei + causal softmax + PV for a ROW QUAD (round-13 phase 2
// as a standalone kernel — no coop, full backfill). Block = (b, quad g);
// 512 blocks descending g. Wave w = window j in [128w, 128w+128); lane holds
// 2 j's. The 2 f2 AkT loads per c-step feed ALL FOUR rows (AkT/V L2 traffic
// halved vs the round-10 pair version). aq/W2 are wave-uniform scalar loads.
// No cross-lane ops in the c-loop; per-row window softmax (6+6 shfl);
// PV shares V loads 4 ways; in-block flash merge. b2 cancels.
// ---------------------------------------------------------------------------
__global__ __launch_bounds__(256) void k_fused(
    const float* __restrict__ Aq, const float* __restrict__ AkT,
    const float* __restrict__ Vv, const float* __restrict__ W2,
    float* __restrict__ out)
{
    __shared__ float pbuf[4][4][128];
    __shared__ float accs[4][4][64];
    __shared__ float mls[4][4][2];

    const int t = threadIdx.x;
    const int bx = blockIdx.x;         // 0..511
    const int b = bx & 3;
    const int g = 127 - (bx >> 2);     // descending: heavy quads first
    const int r0 = g * 4;
    const int w = t >> 6, lane = t & 63;
    const int j0 = w * 128;
    const int jA = j0 + lane * 2;

    float m0 = -1e30f, m1 = -1e30f, m2 = -1e30f, m3 = -1e30f;
    float l0 = 0.f, l1 = 0.f, l2 = 0.f, l3 = 0.f;
    float a0 = 0.f, a1 = 0.f, a2 = 0.f, a3 = 0.f;

    if (j0 <= r0 + 3) {  // wave's window causally live for at least one row
        const float* aq0 = Aq + (size_t)(b * 512 + r0) * 128;
        const float* aq1 = aq0 + 128;
        const float* aq2 = aq1 + 128;
        const float* aq3 = aq2 + 128;
        const float* akt = AkT + (size_t)b * 65536 + jA;

        f2 s0a = {0,0}, s0b = {0,0}, s1a = {0,0}, s1b = {0,0};
        f2 s2a = {0,0}, s2b = {0,0}, s3a = {0,0}, s3b = {0,0};
#pragma unroll 4
        for (int c = 0; c < 128; c += 2) {
            const f2 k0 = *(const f2*)(akt + (size_t)c * 512);
            const f2 k1 = *(const f2*)(akt + (size_t)(c + 1) * 512);
            const float w0 = W2[c], w1 = W2[c + 1];
            s0a += relu2(k0 + aq0[c]) * w0;  s0b += relu2(k1 + aq0[c + 1]) * w1;
            s1a += relu2(k0 + aq1[c]) * w0;  s1b += relu2(k1 + aq1[c + 1]) * w1;
            s2a += relu2(k0 + aq2[c]) * w0;  s2b += relu2(k1 + aq2[c + 1]) * w1;
            s3a += relu2(k0 + aq3[c]) * w0;  s3b += relu2(k1 + aq3[c + 1]) * w1;
        }

#define FINROW(R, SA, SB, MD, LD)                                        \
        {                                                                \
            const int rr_ = r0 + (R);                                    \
            f2 sv = (SA + SB) * SCALE_;                                  \
            float sx = (jA     <= rr_) ? sv.x : -1e30f;                  \
            float sy = (jA + 1 <= rr_) ? sv.y : -1e30f;                  \
            float mx = fmaxf(sx, sy);                                    \
            _Pragma("unroll")                                            \
            for (int off = 1; off < 64; off <<= 1)                       \
                mx = fmaxf(mx, __shfl_xor(mx, off));                     \
            const bool live_ = (j0 <= rr_);                              \
            const float px = live_ ? __expf(sx - mx) : 0.f;              \
            const float py = live_ ? __expf(sy - mx) : 0.f;              \
            f2 pp = {px, py};                                            \
            *(f2*)&pbuf[w][R][lane * 2] = pp;                            \
            float ls = px + py;                                          \
            _Pragma("unroll")                                            \
            for (int off = 1; off < 64; off <<= 1)                       \
                ls += __shfl_xor(ls, off);                               \
            MD = live_ ? mx : -1e30f;                                    \
            LD = ls;                                                     \
        }
        FINROW(0, s0a, s0b, m0, l0)
        FINROW(1, s1a, s1b, m1, l1)
        FINROW(2, s2a, s2b, m2, l2)
        FINROW(3, s3a, s3b, m3, l3)
#undef FINROW

        // ---- PV over the window; lane = h; V loads shared by 4 rows ----
        const float* vt = Vv + ((size_t)b * 512 + j0) * 64 + lane;
#pragma unroll 4
        for (int q4 = 0; q4 < 32; ++q4) {
            const f4 p0 = *(const f4*)&pbuf[w][0][q4 * 4];
            const f4 p1 = *(const f4*)&pbuf[w][1][q4 * 4];
            const f4 p2 = *(const f4*)&pbuf[w][2][q4 * 4];
            const f4 p3 = *(const f4*)&pbuf[w][3][q4 * 4];
            const float v0 = vt[(q4 * 4 + 0) * 64];
            const float v1 = vt[(q4 * 4 + 1) * 64];
            const float v2 = vt[(q4 * 4 + 2) * 64];
            const float v3 = vt[(q4 * 4 + 3) * 64];
            a0 += p0.x * v0 + p0.y * v1 + p0.z * v2 + p0.w * v3;
            a1 += p1.x * v0 + p1.y * v1 + p1.z * v2 + p1.w * v3;
            a2 += p2.x * v0 + p2.y * v1 + p2.z * v2 + p2.w * v3;
            a3 += p3.x * v0 + p3.y * v1 + p3.z * v2 + p3.w * v3;
        }
    }

    // ---- partials to LDS; in-block flash merge ----
    accs[w][0][lane] = a0;
    accs[w][1][lane] = a1;
    accs[w][2][lane] = a2;
    accs[w][3][lane] = a3;
    if (lane == 0) {
        mls[w][0][0] = m0; mls[w][0][1] = l0;
        mls[w][1][0] = m1; mls[w][1][1] = l1;
        mls[w][2][0] = m2; mls[w][2][1] = l2;
        mls[w][3][0] = m3; mls[w][3][1] = l3;
    }
    __syncthreads();

    // wave w merges row r0 + w over its nw live windows
    const int rr = r0 + w;
    const int nw = (rr >> 7) + 1;
    float ms = -1e30f;
    for (int ww = 0; ww < nw; ++ww) ms = fmaxf(ms, mls[ww][w][0]);
    float num = 0.f, den = 0.f;
    for (int ww = 0; ww < nw; ++ww) {
        const float e = __expf(mls[ww][w][0] - ms);
        den += mls[ww][w][1] * e;
        num += accs[ww][w][lane] * e;
    }
    out[(size_t)(b * 512 + rr) * 64 + lane] = num / den;
}

// ---------------------------------------------------------------------------
extern "C" void kernel_launch(void* const* d_in, const int* in_sizes, int n_in,
                              void* d_out, int out_size, void* d_ws, size_t ws_size,
                              hipStream_t stream)
{
    const float* x   = (const float*)d_in[0];
    const float* pos = (const float*)d_in[1];
    const float* W1  = (const float*)d_in[2];
    const float* b1  = (const float*)d_in[3];
    const float* W2  = (const float*)d_in[4];
    const float* b2  = (const float*)d_in[5];  (void)b2;  // cancels in softmax
    const float* Wv  = (const float*)d_in[6];
    float* out = (float*)d_out;
    float* ws = (float*)d_ws;

    float* Aq  = ws;                 // B*T*C = 262144
    float* AkT = ws + 262144;        // B*C*T = 262144 (transposed)
    float* V   = ws + 524288;        // B*T*HS = 131072

    k_prep<<<dim3(256), dim3(640), 0, stream>>>(x, pos, W1, b1, Wv, Aq, AkT, V);
    k_fused<<<dim3(512), dim3(256), 0, stream>>>(Aq, AkT, V, W2, out);
}

// Round 15
// 33.280 us; speedup vs baseline: 2.8515x; 1.0416x over previous
//
#include <hip/hip_runtime.h>
#include <math.h>

#define B_ 4
#define T_ 512
#define C_ 128
#define HS_ 64

typedef float f4 __attribute__((ext_vector_type(4)));
typedef float f2 __attribute__((ext_vector_type(2)));

// scale = C^-0.5
#define SCALE_ 0.08838834764831845f

static __device__ __forceinline__ f2 relu2(f2 v) {
    v.x = fmaxf(v.x, 0.f);
    v.y = fmaxf(v.y, 0.f);
    return v;
}

// ---------------------------------------------------------------------------
// Kernel 1: prep.  x1 = x + pos_emb;  Aq = x1@W1q + b1;  AkT = (x1@W1k)^T;
// V = x@Wv.  256 blocks x 640 threads, block = 8 rows.  (round 10 verbatim)
// ---------------------------------------------------------------------------
__global__ __launch_bounds__(640) void k_prep(
    const float* __restrict__ x, const float* __restrict__ pos,
    const float* __restrict__ W1, const float* __restrict__ b1,
    const float* __restrict__ Wv,
    float* __restrict__ Aq, float* __restrict__ AkT, float* __restrict__ V)
{
    __shared__ float x1s[8 * 132];
    __shared__ float xs[8 * 132];
    const int t = threadIdx.x;
    const int row0 = blockIdx.x * 8;  // over B*T = 2048

    if (t < 256) {
        int r = t >> 5, cq = t & 31;
        int gr = row0 + r;
        f4 xv = *(const f4*)(x + gr * 128 + cq * 4);
        f4 pv = *(const f4*)(pos + (gr & 511) * 128 + cq * 4);
        *(f4*)&xs[r * 132 + cq * 4] = xv;
        *(f4*)&x1s[r * 132 + cq * 4] = xv + pv;
    }
    __syncthreads();

    const int q = t >> 3;   // 0..79 col-quad
    const int r = t & 7;    // row in tile

    const float* wbase;
    int wstr, col0;
    const float* xb;
    f4 binit = {0.f, 0.f, 0.f, 0.f};
    if (q < 32) {
        col0 = q * 4;
        wbase = W1 + 128 * 128 + col0;  // W1q rows (c-major)
        wstr = 128;
        xb = x1s;
        binit = *(const f4*)(b1 + col0);
    } else if (q < 64) {
        col0 = (q - 32) * 4;
        wbase = W1 + col0;  // W1k rows
        wstr = 128;
        xb = x1s;
    } else {
        col0 = (q - 64) * 4;
        wbase = Wv + col0;
        wstr = 64;
        xb = xs;
    }

    f4 acc = binit;
    const float* xr = xb + r * 132;
#pragma unroll 8
    for (int c = 0; c < 128; ++c) {
        f4 w = *(const f4*)(wbase + c * wstr);
        acc += xr[c] * w;
    }

    const int gr = row0 + r;
    if (q < 32) {
        *(f4*)(Aq + (size_t)gr * 128 + col0) = acc;
    } else if (q < 64) {
        const int bb = gr >> 9, j = gr & 511;
        float* base = AkT + ((size_t)bb * 128 + col0) * 512 + j;
        base[0]    = acc.x;
        base[512]  = acc.y;
        base[1024] = acc.z;
        base[1536] = acc.w;
    } else {
        *(f4*)(V + (size_t)gr * 64 + col0) = acc;
    }
}

// ---------------------------------------------------------------------------
// Kernel 2: fused wei + causal softmax + PV for a ROW QUAD, BALANCED chunks.
// Block = (b, quad g), 512 blocks descending g, 4 waves.
// Round 14 gave wave w the fixed window [128w,128w+128): for g>=31 wave 0
// always ran 128 j while waves 2-3 idled (critical path ~1.74x ideal).
// Now: nj = 4g+4 live j's, cj = ceil(nj/8)*2 <= 128; wave w owns the chunk
// [w*cj, min((w+1)*cj, nj)). Equal work per wave, single <=128-j tile per
// wave (no online rescale), same c-loop / softmax / PV / in-block merge.
// Masks: element live iff jA <= min(jend-1, rr); row live iff jstart <= rr.
// ---------------------------------------------------------------------------
__global__ __launch_bounds__(256, 4) void k_fused(
    const float* __restrict__ Aq, const float* __restrict__ AkT,
    const float* __restrict__ Vv, const float* __restrict__ W2,
    float* __restrict__ out)
{
    __shared__ float pbuf[4][4][128];
    __shared__ float accs[4][4][64];
    __shared__ float mls[4][4][2];

    const int t = threadIdx.x;
    const int bx = blockIdx.x;         // 0..511
    const int b = bx & 3;
    const int g = 127 - (bx >> 2);     // descending: heavy quads first
    const int r0 = g * 4;
    const int w = t >> 6, lane = t & 63;

    const int nj = r0 + 4;                      // live j count for this quad
    const int cj = ((nj + 7) >> 3) << 1;        // per-wave chunk, even, <=128
    const int jstart = w * cj;
    const int jend = min(jstart + cj, nj);
    const int jA = jstart + lane * 2;

    float m0 = -1e30f, m1 = -1e30f, m2 = -1e30f, m3 = -1e30f;
    float l0 = 0.f, l1 = 0.f, l2 = 0.f, l3 = 0.f;
    float a0 = 0.f, a1 = 0.f, a2 = 0.f, a3 = 0.f;

    if (jstart < jend) {
        const float* aq0 = Aq + (size_t)(b * 512 + r0) * 128;
        const float* aq1 = aq0 + 128;
        const float* aq2 = aq1 + 128;
        const float* aq3 = aq2 + 128;
        const float* akt = AkT + (size_t)b * 65536 + jA;  // jA <= 510 always

        f2 s0a = {0,0}, s0b = {0,0}, s1a = {0,0}, s1b = {0,0};
        f2 s2a = {0,0}, s2b = {0,0}, s3a = {0,0}, s3b = {0,0};
#pragma unroll 4
        for (int c = 0; c < 128; c += 2) {
            const f2 k0 = *(const f2*)(akt + (size_t)c * 512);
            const f2 k1 = *(const f2*)(akt + (size_t)(c + 1) * 512);
            const float w0 = W2[c], w1 = W2[c + 1];
            s0a += relu2(k0 + aq0[c]) * w0;  s0b += relu2(k1 + aq0[c + 1]) * w1;
            s1a += relu2(k0 + aq1[c]) * w0;  s1b += relu2(k1 + aq1[c + 1]) * w1;
            s2a += relu2(k0 + aq2[c]) * w0;  s2b += relu2(k1 + aq2[c + 1]) * w1;
            s3a += relu2(k0 + aq3[c]) * w0;  s3b += relu2(k1 + aq3[c + 1]) * w1;
        }

#define FINROW(R, SA, SB, MD, LD)                                        \
        {                                                                \
            const int rr_ = r0 + (R);                                    \
            const int jlim_ = min(jend - 1, rr_);                        \
            f2 sv = (SA + SB) * SCALE_;                                  \
            float sx = (jA     <= jlim_) ? sv.x : -1e30f;                \
            float sy = (jA + 1 <= jlim_) ? sv.y : -1e30f;                \
            float mx = fmaxf(sx, sy);                                    \
            _Pragma("unroll")                                            \
            for (int off = 1; off < 64; off <<= 1)                       \
                mx = fmaxf(mx, __shfl_xor(mx, off));                     \
            const bool live_ = (jstart <= rr_);                          \
            const float px = live_ ? __expf(sx - mx) : 0.f;              \
            const float py = live_ ? __expf(sy - mx) : 0.f;              \
            f2 pp = {px, py};                                            \
            *(f2*)&pbuf[w][R][lane * 2] = pp;                            \
            float ls = px + py;                                          \
            _Pragma("unroll")                                            \
            for (int off = 1; off < 64; off <<= 1)                       \
                ls += __shfl_xor(ls, off);                               \
            MD = live_ ? mx : -1e30f;                                    \
            LD = ls;                                                     \
        }
        FINROW(0, s0a, s0b, m0, l0)
        FINROW(1, s1a, s1b, m1, l1)
        FINROW(2, s2a, s2b, m2, l2)
        FINROW(3, s3a, s3b, m3, l3)
#undef FINROW

        // ---- PV over the chunk; lane = h; V loads shared by 4 rows ----
        const float* vt = Vv + ((size_t)b * 512 + jstart) * 64 + lane;
        const int q4max = (jend - jstart + 3) >> 2;
        for (int q4 = 0; q4 < q4max; ++q4) {
            const f4 p0 = *(const f4*)&pbuf[w][0][q4 * 4];
            const f4 p1 = *(const f4*)&pbuf[w][1][q4 * 4];
            const f4 p2 = *(const f4*)&pbuf[w][2][q4 * 4];
            const f4 p3 = *(const f4*)&pbuf[w][3][q4 * 4];
            const float v0 = vt[(q4 * 4 + 0) * 64];
            const float v1 = vt[(q4 * 4 + 1) * 64];
            const float v2 = vt[(q4 * 4 + 2) * 64];
            const float v3 = vt[(q4 * 4 + 3) * 64];
            a0 += p0.x * v0 + p0.y * v1 + p0.z * v2 + p0.w * v3;
            a1 += p1.x * v0 + p1.y * v1 + p1.z * v2 + p1.w * v3;
            a2 += p2.x * v0 + p2.y * v1 + p2.z * v2 + p2.w * v3;
            a3 += p3.x * v0 + p3.y * v1 + p3.z * v2 + p3.w * v3;
        }
    }

    // ---- partials to LDS; in-block flash merge ----
    accs[w][0][lane] = a0;
    accs[w][1][lane] = a1;
    accs[w][2][lane] = a2;
    accs[w][3][lane] = a3;
    if (lane == 0) {
        mls[w][0][0] = m0; mls[w][0][1] = l0;
        mls[w][1][0] = m1; mls[w][1][1] = l1;
        mls[w][2][0] = m2; mls[w][2][1] = l2;
        mls[w][3][0] = m3; mls[w][3][1] = l3;
    }
    __syncthreads();

    // wave w merges row r0 + w over all 4 wave partials
    const int rr = r0 + w;
    float ms = -1e30f;
#pragma unroll
    for (int ww = 0; ww < 4; ++ww) ms = fmaxf(ms, mls[ww][w][0]);
    float num = 0.f, den = 0.f;
#pragma unroll
    for (int ww = 0; ww < 4; ++ww) {
        const float e = __expf(mls[ww][w][0] - ms);
        den += mls[ww][w][1] * e;
        num += accs[ww][w][lane] * e;
    }
    out[(size_t)(b * 512 + rr) * 64 + lane] = num / den;
}

// ---------------------------------------------------------------------------
extern "C" void kernel_launch(void* const* d_in, const int* in_sizes, int n_in,
                              void* d_out, int out_size, void* d_ws, size_t ws_size,
                              hipStream_t stream)
{
    const float* x   = (const float*)d_in[0];
    const float* pos = (const float*)d_in[1];
    const float* W1  = (const float*)d_in[2];
    const float* b1  = (const float*)d_in[3];
    const float* W2  = (const float*)d_in[4];
    const float* b2  = (const float*)d_in[5];  (void)b2;  // cancels in softmax
    const float* Wv  = (const float*)d_in[6];
    float* out = (float*)d_out;
    float* ws = (float*)d_ws;

    float* Aq  = ws;                 // B*T*C = 262144
    float* AkT = ws + 262144;        // B*C*T = 262144 (transposed)
    float* V   = ws + 524288;        // B*T*HS = 131072

    k_prep<<<dim3(256), dim3(640), 0, stream>>>(x, pos, W1, b1, Wv, Aq, AkT, V);
    k_fused<<<dim3(512), dim3(256), 0, stream>>>(Aq, AkT, V, W2, out);
}